// Round 2
// baseline (534.057 us; speedup 1.0000x reference)
//
#include <hip/hip_runtime.h>
#include <math.h>

// Problem constants
#define B_  32
#define S_  2048
#define E_  1024   // 2*HIDDEN
#define A_  512    // ATT
#define H_  512

#define MB   128             // rows (s) per fused block
#define NCH  (S_ / MB)       // 16 chunks per batch row
#define KT   32              // K per MFMA step
#define NK   (E_ / KT)       // 32 K-iterations

typedef __bf16 bf16;
typedef __attribute__((ext_vector_type(8))) __bf16 bf16x8;
typedef __attribute__((ext_vector_type(4))) float  f32x4;

__device__ __forceinline__ float fast_tanh(float x) {
    x = fminf(fmaxf(x, -15.f), 15.f);
    const float e = __expf(2.f * x);
    return (e - 1.f) / (e + 1.f);
}

// ---------------------------------------------------------------------------
// prep kernel: blocks 0..127  : split W_enc into bf16 hi/lo, transposed [a][k]
//              blocks 128..383: dec_att k-split partials dp[seg][b][a]
// ---------------------------------------------------------------------------
__global__ __launch_bounds__(256)
void prep_kernel(const float* __restrict__ Wenc,
                 const float* __restrict__ dh,
                 const float* __restrict__ Wdec,
                 const float* __restrict__ bdec,
                 bf16* __restrict__ Whi, bf16* __restrict__ Wlo,
                 float* __restrict__ dp) {
    const int t = threadIdx.x;
    if (blockIdx.x < 128) {
        __shared__ float tile[64][65];
        const int kb = blockIdx.x >> 3;      // 0..15
        const int ab = blockIdx.x & 7;       // 0..7
        const int k0 = kb * 64, a0 = ab * 64;
#pragma unroll
        for (int p = 0; p < 8; ++p) {
            const int kk = p * 8 + (t >> 5);
            const int aa = (t & 31) * 2;
            const float2 v = *(const float2*)&Wenc[(size_t)(k0 + kk) * A_ + a0 + aa];
            tile[kk][aa]     = v.x;
            tile[kk][aa + 1] = v.y;
        }
        __syncthreads();
        const int aa  = t >> 2;
        const int kk0 = (t & 3) * 16;
        bf16x8 hv0, hv1, lv0, lv1;
#pragma unroll
        for (int j = 0; j < 16; ++j) {
            const float x = tile[kk0 + j][aa];
            const bf16 h = (bf16)x;
            const bf16 l = (bf16)(x - (float)h);
            if (j < 8) { hv0[j] = h; lv0[j] = l; }
            else       { hv1[j - 8] = h; lv1[j - 8] = l; }
        }
        bf16* dh_ = Whi + (size_t)(a0 + aa) * E_ + k0 + kk0;
        bf16* dl_ = Wlo + (size_t)(a0 + aa) * E_ + k0 + kk0;
        *(bf16x8*)dh_ = hv0; *((bf16x8*)dh_ + 1) = hv1;
        *(bf16x8*)dl_ = lv0; *((bf16x8*)dl_ + 1) = lv1;
    } else {
        __shared__ float dhl[64];
        const int idx = blockIdx.x - 128;
        const int b   = idx >> 3;
        const int seg = idx & 7;
        if (t < 64) dhl[t] = dh[b * H_ + seg * 64 + t];
        __syncthreads();
        const int a0 = t, a1 = t + 256;
        float acc0 = 0.f, acc1 = 0.f;
        const float* Wrow = Wdec + (size_t)(seg * 64) * A_;
#pragma unroll 8
        for (int h = 0; h < 64; ++h) {
            const float s = dhl[h];
            acc0 += s * Wrow[h * A_ + a0];
            acc1 += s * Wrow[h * A_ + a1];
        }
        if (seg == 0) { acc0 += bdec[a0]; acc1 += bdec[a1]; }
        dp[(size_t)(seg * B_ + b) * A_ + a0] = acc0;
        dp[(size_t)(seg * B_ + b) * A_ + a1] = acc1;
    }
}

// ---------------------------------------------------------------------------
// Fused kernel: bf16x2-split MFMA GEMM (128 x 512 x 1024 per block) +
// tanh score + masked softmax partials + ctx partials.
//
// v2 structure: W (hi/lo) fragments are loaded DIRECTLY global->registers,
// double-buffered one K-step ahead (W is 2 MB -> L2-resident; the per-lane
// row-strided 16B accesses coalesce into 16 fully-used 64B lines per
// instruction, identical to the old glds pattern). LDS holds only the A
// double-buffer (32 KB). One lgkm-only raw barrier per K-step: in-flight
// global loads (W[kt+1], A fp32 2-deep) are never drained at barriers.
// ---------------------------------------------------------------------------
__global__ __launch_bounds__(512, 2)
void fused_kernel(const float* __restrict__ enc,     // [B,S,E] fp32
                  const int*   __restrict__ masks,   // [B,S]
                  const bf16*  __restrict__ Whi_g,   // [A,E] bf16 (W^T hi)
                  const bf16*  __restrict__ Wlo_g,   // [A,E] bf16 (W^T lo)
                  const float* __restrict__ benc,    // [A]
                  const float* __restrict__ Watt,    // [A]
                  const float* __restrict__ batt,    // [1]
                  const float* __restrict__ dp,      // [8,B,A] dec_att parts
                  float* __restrict__ pm,            // [B*NCH]
                  float* __restrict__ pl,            // [B*NCH]
                  float* __restrict__ pctx) {        // [B*NCH, A]
    __shared__ union {
        struct {
            __align__(16) bf16 Ab[2][2][MB * KT];     // 32 KB dbuf [buf][hi/lo]
        } k;
        struct {
            float decl[A_], wattl[A_], bencl[A_];     // 6 KB
            float red[MB * 8];                        // 4 KB
            float score[MB], p[MB];                   // 1 KB
            int   mask[MB];                           // 0.5 KB
        } e;
    } sm;                                             // 32 KB total

    const int t    = threadIdx.x;
    const int wv   = t >> 6;      // wave 0..7
    const int L    = t & 63;      // lane
    const int quad = L >> 4;      // 0..3
    const int colL = L & 15;      // 0..15
    const int b    = blockIdx.x >> 4;
    const int ch   = blockIdx.x & 15;
    const int s0   = ch * MB;

    const float* encB = enc + ((size_t)(b * S_ + s0)) * E_;

    f32x4 acc[8][4];
#pragma unroll
    for (int mt = 0; mt < 8; ++mt)
#pragma unroll
        for (int nt = 0; nt < 4; ++nt) acc[mt][nt] = (f32x4){0.f, 0.f, 0.f, 0.f};

    // ---- A staging: thread t -> row t>>2, k-quad t&3 (8 consecutive k)
    const int arow = t >> 2;
    const int akq  = t & 3;
    const int a_wr = ((arow >> 4) * 512) + akq * 128 +
                     (((arow & 15) ^ (akq << 2)) * 8);     // swizzled elem off
    const float* aptr = encB + (size_t)arow * E_ + akq * 8;
    const int a_rd = quad * 128 + (((L & 15) ^ (quad << 2)) * 8);

    // ---- per-lane W fragment base: row (wv*64 + nt*16 + colL), k-chunk quad*8
    const bf16* wHi = Whi_g + (size_t)(wv * 64 + colL) * E_ + quad * 8;
    const bf16* wLo = Wlo_g + (size_t)(wv * 64 + colL) * E_ + quad * 8;

    bf16x8 bh0[4], bl0[4], bh1[4], bl1[4];
    float4 cA0, cB0, cA1, cB1;

    // ================= prologue: A[0] -> LDS, W[0] -> regs, A[1] in flight ==
    cA0 = *(const float4*)(aptr);
    cB0 = *(const float4*)(aptr + 4);
#pragma unroll
    for (int nt = 0; nt < 4; ++nt) {
        bh0[nt] = *(const bf16x8*)(wHi + (size_t)nt * (16 * E_));
        bl0[nt] = *(const bf16x8*)(wLo + (size_t)nt * (16 * E_));
    }
    cA1 = *(const float4*)(aptr + KT);
    cB1 = *(const float4*)(aptr + KT + 4);
    {
        const float xs[8] = {cA0.x, cA0.y, cA0.z, cA0.w, cB0.x, cB0.y, cB0.z, cB0.w};
        bf16x8 hv, lv;
#pragma unroll
        for (int j = 0; j < 8; ++j) {
            const bf16 h = (bf16)xs[j];
            hv[j] = h; lv[j] = (bf16)(xs[j] - (float)h);
        }
        *(bf16x8*)&sm.k.Ab[0][0][a_wr] = hv;
        *(bf16x8*)&sm.k.Ab[0][1][a_wr] = lv;
    }
    asm volatile("s_waitcnt lgkmcnt(0)" ::: "memory");
    __builtin_amdgcn_s_barrier();
    asm volatile("" ::: "memory");

    // ================= K loop (unroll-2 ping/pong, all static indexing) =====
    // Invariant at top of step kt: regs BH/BL = W[kt]; LDS buf[kt&1] = A[kt];
    // fp32 regs PA/PB = A[kt+1] (in flight or landed).
#define STEP(KT_, BH, BL, BHN, BLN, PA, PB, QA, QB)                            \
    {                                                                          \
        const int ktn_ = (KT_) + 1;                                            \
        if (ktn_ < NK) {                                                       \
            _Pragma("unroll")                                                  \
            for (int nt = 0; nt < 4; ++nt) {                                   \
                BHN[nt] = *(const bf16x8*)(wHi + (size_t)nt * (16 * E_) +      \
                                           (size_t)ktn_ * KT);                 \
                BLN[nt] = *(const bf16x8*)(wLo + (size_t)nt * (16 * E_) +      \
                                           (size_t)ktn_ * KT);                 \
            }                                                                  \
        }                                                                      \
        if ((KT_) + 2 < NK) {                                                  \
            const float* np_ = aptr + (size_t)((KT_) + 2) * KT;                \
            QA = *(const float4*)(np_);                                        \
            QB = *(const float4*)(np_ + 4);                                    \
        }                                                                      \
        const bf16* Ahi_ = sm.k.Ab[(KT_) & 1][0];                              \
        const bf16* Alo_ = sm.k.Ab[(KT_) & 1][1];                              \
        _Pragma("unroll")                                                      \
        for (int mt = 0; mt < 8; ++mt) {                                       \
            const bf16x8 ah = *(const bf16x8*)&Ahi_[mt * 512 + a_rd];          \
            const bf16x8 al = *(const bf16x8*)&Alo_[mt * 512 + a_rd];          \
            _Pragma("unroll")                                                  \
            for (int nt = 0; nt < 4; ++nt) {                                   \
                acc[mt][nt] = __builtin_amdgcn_mfma_f32_16x16x32_bf16(         \
                    ah, BH[nt], acc[mt][nt], 0, 0, 0);                         \
                acc[mt][nt] = __builtin_amdgcn_mfma_f32_16x16x32_bf16(         \
                    al, BH[nt], acc[mt][nt], 0, 0, 0);                         \
                acc[mt][nt] = __builtin_amdgcn_mfma_f32_16x16x32_bf16(         \
                    ah, BL[nt], acc[mt][nt], 0, 0, 0);                         \
            }                                                                  \
        }                                                                      \
        if (ktn_ < NK) {                                                       \
            const float xs_[8] = {PA.x, PA.y, PA.z, PA.w,                      \
                                  PB.x, PB.y, PB.z, PB.w};                     \
            bf16x8 hv_, lv_;                                                   \
            _Pragma("unroll")                                                  \
            for (int j = 0; j < 8; ++j) {                                      \
                const bf16 h_ = (bf16)xs_[j];                                  \
                hv_[j] = h_; lv_[j] = (bf16)(xs_[j] - (float)h_);              \
            }                                                                  \
            *(bf16x8*)&sm.k.Ab[ktn_ & 1][0][a_wr] = hv_;                       \
            *(bf16x8*)&sm.k.Ab[ktn_ & 1][1][a_wr] = lv_;                       \
            asm volatile("s_waitcnt lgkmcnt(0)" ::: "memory");                 \
            __builtin_amdgcn_s_barrier();                                      \
            asm volatile("" ::: "memory");                                     \
        }                                                                      \
    }

    for (int kt = 0; kt < NK; kt += 2) {
        STEP(kt,     bh0, bl0, bh1, bl1, cA1, cB1, cA0, cB0);
        STEP(kt + 1, bh1, bl1, bh0, bl0, cA0, cB0, cA1, cB1);
    }
#undef STEP

    // ================= epilogue =================
    __syncthreads();   // all K-loop LDS reads done before union is repurposed
    {
        float d = 0.f;
#pragma unroll
        for (int g = 0; g < 8; ++g) d += dp[(size_t)(g * B_ + b) * A_ + t];
        sm.e.decl[t]  = d;                 // t < 512 == A_
        sm.e.wattl[t] = Watt[t];
        sm.e.bencl[t] = benc[t];
        if (t < MB) sm.e.mask[t] = masks[(size_t)b * S_ + s0 + t];
    }
    __syncthreads();

    float sp[8][4];
#pragma unroll
    for (int mt = 0; mt < 8; ++mt)
#pragma unroll
        for (int r = 0; r < 4; ++r) sp[mt][r] = 0.f;

#pragma unroll
    for (int nt = 0; nt < 4; ++nt) {
        const int cg = wv * 64 + nt * 16 + colL;
        const float bv  = sm.e.bencl[cg];
        const float dv  = sm.e.decl[cg];
        const float wav = sm.e.wattl[cg];
#pragma unroll
        for (int mt = 0; mt < 8; ++mt)
#pragma unroll
            for (int r = 0; r < 4; ++r) {
                const float ea = acc[mt][nt][r] + bv;
                acc[mt][nt][r] = ea;
                sp[mt][r] += fast_tanh(ea + dv) * wav;
            }
    }
#pragma unroll
    for (int d = 1; d < 16; d <<= 1)
#pragma unroll
        for (int mt = 0; mt < 8; ++mt)
#pragma unroll
            for (int r = 0; r < 4; ++r)
                sp[mt][r] += __shfl_xor(sp[mt][r], d);
    if (colL == 0) {
#pragma unroll
        for (int mt = 0; mt < 8; ++mt)
#pragma unroll
            for (int r = 0; r < 4; ++r)
                sm.e.red[(mt * 16 + quad * 4 + r) * 8 + wv] = sp[mt][r];
    }
    __syncthreads();

    if (t < MB) {
        float s = 0.f;
#pragma unroll
        for (int j = 0; j < 8; ++j) s += sm.e.red[t * 8 + j];
        sm.e.score[t] = s + batt[0];
    }
    __syncthreads();

    float m_loc = -1e30f;
    for (int r = 0; r < MB; ++r)
        if (!sm.e.mask[r]) m_loc = fmaxf(m_loc, sm.e.score[r]);
    if (t < MB) sm.e.p[t] = sm.e.mask[t] ? 0.f : __expf(sm.e.score[t] - m_loc);
    __syncthreads();

    float ctxl[4] = {0.f, 0.f, 0.f, 0.f};
#pragma unroll
    for (int mt = 0; mt < 8; ++mt)
#pragma unroll
        for (int r = 0; r < 4; ++r) {
            const float p = sm.e.p[mt * 16 + quad * 4 + r];
#pragma unroll
            for (int nt = 0; nt < 4; ++nt) ctxl[nt] += p * acc[mt][nt][r];
        }
#pragma unroll
    for (int nt = 0; nt < 4; ++nt) {
        ctxl[nt] += __shfl_xor(ctxl[nt], 16);
        ctxl[nt] += __shfl_xor(ctxl[nt], 32);
    }
    if (quad == 0) {
#pragma unroll
        for (int nt = 0; nt < 4; ++nt)
            pctx[(size_t)blockIdx.x * A_ + wv * 64 + nt * 16 + colL] = ctxl[nt];
    }
    if (t == 0) {
        float l = 0.f;
        for (int r = 0; r < MB; ++r) l += sm.e.p[r];
        pm[blockIdx.x] = m_loc;
        pl[blockIdx.x] = l;
    }
}

// ---------------------------------------------------------------------------
// Combine: merge NCH chunk partials per batch row
// ---------------------------------------------------------------------------
__global__ __launch_bounds__(512)
void combine_kernel(const float* __restrict__ pm,
                    const float* __restrict__ pl,
                    const float* __restrict__ pctx,
                    float* __restrict__ out) {
    const int b = blockIdx.x;
    const int t = threadIdx.x;
    float m_g = -1e30f;
    for (int c = 0; c < NCH; ++c) m_g = fmaxf(m_g, pm[b * NCH + c]);
    float L = 0.f;
    for (int c = 0; c < NCH; ++c)
        L += pl[b * NCH + c] * __expf(pm[b * NCH + c] - m_g);
    const float inv = 1.f / L;
    float s = 0.f;
    for (int c = 0; c < NCH; ++c)
        s += pctx[((size_t)b * NCH + c) * A_ + t] * __expf(pm[b * NCH + c] - m_g);
    out[b * A_ + t] = s * inv;
}

// ---------------------------------------------------------------------------
extern "C" void kernel_launch(void* const* d_in, const int* in_sizes, int n_in,
                              void* d_out, int out_size, void* d_ws, size_t ws_size,
                              hipStream_t stream) {
    const float* enc  = (const float*)d_in[0];   // [B,S,2H] fp32
    const float* dh   = (const float*)d_in[1];   // [B,H]
    const int*   mks  = (const int*)  d_in[2];   // [B,S,1] bool->int
    const float* Wenc = (const float*)d_in[3];   // [2H,A]
    const float* benc = (const float*)d_in[4];   // [A]
    const float* Wdec = (const float*)d_in[5];   // [H,A]
    const float* bdec = (const float*)d_in[6];   // [A]
    const float* Watt = (const float*)d_in[7];   // [A]
    const float* batt = (const float*)d_in[8];   // [1]
    float* out = (float*)d_out;

    float* ws   = (float*)d_ws;
    float* pm   = ws;                             // 512 f
    float* pl   = pm + B_ * NCH;                  // 512 f
    float* pctx = pl + B_ * NCH;                  // 262144 f
    float* dp   = pctx + (size_t)B_ * NCH * A_;   // 131072 f
    bf16*  Whi  = (bf16*)(dp + 8 * B_ * A_);      // 1 MB
    bf16*  Wlo  = Whi + (size_t)A_ * E_;          // 1 MB
    (void)in_sizes; (void)n_in; (void)out_size; (void)ws_size;

    prep_kernel<<<384, 256, 0, stream>>>(Wenc, dh, Wdec, bdec, Whi, Wlo, dp);
    fused_kernel<<<B_ * NCH, 512, 0, stream>>>(
        enc, mks, Whi, Wlo, benc, Watt, batt, dp, pm, pl, pctx);
    combine_kernel<<<B_, 512, 0, stream>>>(pm, pl, pctx, out);
}